// Round 2
// baseline (1250.672 us; speedup 1.0000x reference)
//
#include <hip/hip_runtime.h>
#include <math.h>

#define EPS_C      1e-05f
#define PROJ_EPS_C 0.004f
#define MIN_NORM_C 1e-15f

#define NTOK   4096
#define DH     64
#define TILE   64
#define CHUNK  128
#define NCHUNK (NTOK / CHUNK)
#define PADROW 68   // 64 + 4 pad: float4-aligned rows, bank-stride 16 -> <=2-way

__device__ __forceinline__ float elup(float z) {
    // elu(z) + 1
    return z > 0.f ? z + 1.f : __expf(z);
}

// ---------------------------------------------------------------------------
// Phase 1: from K, V compute per-token pt, and accumulate v2_sum[64] and
// context[64][64] = sum_n v2[n][d] * x_scaled[n][e]  (atomicAdd into ws)
// ---------------------------------------------------------------------------
__global__ __launch_bounds__(256, 4) void glin_phase1(
    const float* __restrict__ Kk, const float* __restrict__ Vv,
    const float* __restrict__ mask, const float* __restrict__ cc,
    int csize, int H,
    float* __restrict__ pt_out, float* __restrict__ v2sum_out,
    float* __restrict__ ctx_out)
{
    __shared__ __align__(16) float v2s[TILE][PADROW];
    __shared__ __align__(16) float xss[TILE][PADROW];

    const int bh    = blockIdx.x;
    const int chunk = blockIdx.y;
    const int h     = bh % H;
    const float k   = cc[(csize == 1) ? 0 : h];

    const float* Kp = Kk + (size_t)bh * NTOK * DH;
    const float* Vp = Vv + (size_t)bh * NTOK * DH;
    float* ptp      = pt_out + (size_t)bh * NTOK;

    const int tid = threadIdx.x;
    const int ty  = tid >> 4;   // 0..15 -> d block
    const int tx  = tid & 15;   // 0..15 -> e block

    float acc[4][4];
#pragma unroll
    for (int i = 0; i < 4; ++i)
#pragma unroll
        for (int j = 0; j < 4; ++j) acc[i][j] = 0.f;
    float v2acc[4] = {0.f, 0.f, 0.f, 0.f};

    const int tbase = chunk * CHUNK;
    for (int tt = 0; tt < CHUNK; tt += TILE) {
        // ---- stage + transform one 64-token tile ----
#pragma unroll
        for (int p = 0; p < 4; ++p) {
            int f   = tid + p * 256;
            int row = f >> 4;       // local token 0..63
            int c4  = f & 15;       // float4 column 0..15
            int gtok = tbase + tt + row;
            float4 v4 = *(const float4*)(Vp + (size_t)gtok * DH + c4 * 4);
            float4 k4 = *(const float4*)(Kp + (size_t)gtok * DH + c4 * 4);
            // ||V_row||^2 via 16-lane reduction (lanes of same row are consecutive)
            float ss = v4.x * v4.x + v4.y * v4.y + v4.z * v4.z + v4.w * v4.w;
            ss += __shfl_xor(ss, 1);
            ss += __shfl_xor(ss, 2);
            ss += __shfl_xor(ss, 4);
            ss += __shfl_xor(ss, 8);
            float dpt   = fmaxf(1.f + k * ss, MIN_NORM_C);
            float pt    = 1.f / dpt;
            float gamma = 2.f * pt;
            float gm1   = gamma - 1.f;
            float sg    = (gm1 < 0.f) ? -1.f : 1.f;   // _sign(0) = +1
            float denomG = sg * fmaxf(fabsf(gm1), 1e-10f);
            float m     = mask[gtok];
            float xsc   = gamma / denomG * m;
            float a2    = denomG * m;
            if (c4 == 0) ptp[gtok] = pt;
            float4 xs4;
            xs4.x = v4.x * xsc; xs4.y = v4.y * xsc;
            xs4.z = v4.z * xsc; xs4.w = v4.w * xsc;
            float4 w4;
            w4.x = a2 * elup(k4.x * pt);
            w4.y = a2 * elup(k4.y * pt);
            w4.z = a2 * elup(k4.z * pt);
            w4.w = a2 * elup(k4.w * pt);
            *(float4*)&xss[row][c4 * 4] = xs4;
            *(float4*)&v2s[row][c4 * 4] = w4;
        }
        __syncthreads();
        // ---- outer-product accumulate: acc[d][e] += v2[t][d] * xs[t][e] ----
#pragma unroll 4
        for (int t = 0; t < TILE; ++t) {
            float4 a = *(const float4*)&v2s[t][ty * 4];
            float4 b = *(const float4*)&xss[t][tx * 4];
            float av[4] = {a.x, a.y, a.z, a.w};
            float bv[4] = {b.x, b.y, b.z, b.w};
#pragma unroll
            for (int i = 0; i < 4; ++i) {
                v2acc[i] += av[i];
#pragma unroll
                for (int j = 0; j < 4; ++j)
                    acc[i][j] = fmaf(av[i], bv[j], acc[i][j]);
            }
        }
        __syncthreads();
    }

    float* ctx = ctx_out + (size_t)bh * DH * DH;
#pragma unroll
    for (int i = 0; i < 4; ++i)
#pragma unroll
        for (int j = 0; j < 4; ++j)
            atomicAdd(&ctx[(ty * 4 + i) * DH + tx * 4 + j], acc[i][j]);
    if (tx == 0) {
#pragma unroll
        for (int i = 0; i < 4; ++i)
            atomicAdd(&v2sum_out[(size_t)bh * DH + ty * 4 + i], v2acc[i]);
    }
}

// ---------------------------------------------------------------------------
// Phase 2: from Q, pt, v2_sum, context compute
//   v1 = elup(Q*pt); D = v1.v2_sum; X = (v1 @ context)/D; project->mobius(0.5)->project
// v1 is kept in NATURAL [token][dim] LDS layout (no transpose -> no bank
// conflicts); the GEMM walks d in blocks of 4 with float4 reads on both sides.
// ---------------------------------------------------------------------------
__global__ __launch_bounds__(256, 4) void glin_phase2(
    const float* __restrict__ Qq, const float* __restrict__ cc,
    int csize, int H,
    const float* __restrict__ pt_in, const float* __restrict__ v2sum_in,
    const float* __restrict__ ctx_in, float* __restrict__ out)
{
    __shared__ __align__(16) float ctxs[DH][PADROW];
    __shared__ __align__(16) float v1s[TILE][PADROW];  // natural [token][dim]
    __shared__ __align__(16) float v2sum[DH];
    __shared__ float dinv[TILE];
    __shared__ __align__(16) float ptl[CHUNK];

    const int bh    = blockIdx.x;
    const int chunk = blockIdx.y;
    const int h     = bh % H;
    const float k   = cc[(csize == 1) ? 0 : h];
    const float sk  = sqrtf(fabsf(k) + MIN_NORM_C);
    const float maxnorm = (k < 0.f) ? (1.f - PROJ_EPS_C) / sk : 1e15f;

    const int tid = threadIdx.x;
    const int ty  = tid >> 4;
    const int tx  = tid & 15;

    const float* Qp = Qq + (size_t)bh * NTOK * DH;
    float* outp     = out + (size_t)bh * NTOK * DH;

    // load context into LDS (padded)
#pragma unroll
    for (int p = 0; p < 4; ++p) {
        int f = tid + p * 256;
        int d = f >> 4, c4 = f & 15;
        float4 v = *(const float4*)(ctx_in + (size_t)bh * DH * DH + d * DH + c4 * 4);
        *(float4*)&ctxs[d][c4 * 4] = v;
    }
    if (tid < 16) {
        float4 v = *(const float4*)(v2sum_in + (size_t)bh * DH + tid * 4);
        *(float4*)&v2sum[tid * 4] = v;
    }
    if (tid < CHUNK / 4) {
        float4 v = *(const float4*)(pt_in + (size_t)bh * NTOK + chunk * CHUNK + tid * 4);
        *(float4*)&ptl[tid * 4] = v;
    }
    __syncthreads();

    const int tbase = chunk * CHUNK;
    for (int tt = 0; tt < CHUNK; tt += TILE) {
        // ---- build v1 tile (natural layout) + Dinv ----
#pragma unroll
        for (int p = 0; p < 4; ++p) {
            int f   = tid + p * 256;
            int row = f >> 4;        // local token 0..63
            int c4  = f & 15;
            int gtok = tbase + tt + row;
            float4 q4 = *(const float4*)(Qp + (size_t)gtok * DH + c4 * 4);
            float ptv = ptl[tt + row];
            float4 v1;
            v1.x = elup(q4.x * ptv);
            v1.y = elup(q4.y * ptv);
            v1.z = elup(q4.z * ptv);
            v1.w = elup(q4.w * ptv);
            float4 vs = *(const float4*)&v2sum[c4 * 4];
            float dp = v1.x * vs.x + v1.y * vs.y + v1.z * vs.z + v1.w * vs.w;
            dp += __shfl_xor(dp, 1);
            dp += __shfl_xor(dp, 2);
            dp += __shfl_xor(dp, 4);
            dp += __shfl_xor(dp, 8);
            if (c4 == 0) {
                float Dv = (dp == 0.f) ? EPS_C : dp;
                dinv[row] = 1.f / Dv;
            }
            *(float4*)&v1s[row][c4 * 4] = v1;
        }
        __syncthreads();
        // ---- X_tile = v1 @ context : 4 tokens x 4 out-dims per thread ----
        float acc[4][4];
#pragma unroll
        for (int i = 0; i < 4; ++i)
#pragma unroll
            for (int j = 0; j < 4; ++j) acc[i][j] = 0.f;
#pragma unroll
        for (int db = 0; db < DH / 4; ++db) {
            float bv[4][4];
#pragma unroll
            for (int u = 0; u < 4; ++u)
                *(float4*)&bv[u][0] = *(const float4*)&ctxs[db * 4 + u][tx * 4];
#pragma unroll
            for (int i = 0; i < 4; ++i) {
                float4 a = *(const float4*)&v1s[ty * 4 + i][db * 4];
#pragma unroll
                for (int j = 0; j < 4; ++j) {
                    acc[i][j] = fmaf(a.x, bv[0][j], acc[i][j]);
                    acc[i][j] = fmaf(a.y, bv[1][j], acc[i][j]);
                    acc[i][j] = fmaf(a.z, bv[2][j], acc[i][j]);
                    acc[i][j] = fmaf(a.w, bv[3][j], acc[i][j]);
                }
            }
        }
        // ---- epilogue: Dinv scale, project -> mobius(0.5) -> project ----
#pragma unroll
        for (int i = 0; i < 4; ++i) {
            int row  = ty * 4 + i;
            float dv = dinv[row];
            float x0 = acc[i][0] * dv;
            float x1 = acc[i][1] * dv;
            float x2 = acc[i][2] * dv;
            float x3 = acc[i][3] * dv;
            float n2 = x0 * x0 + x1 * x1 + x2 * x2 + x3 * x3;
            n2 += __shfl_xor(n2, 1);
            n2 += __shfl_xor(n2, 2);
            n2 += __shfl_xor(n2, 4);
            n2 += __shfl_xor(n2, 8);
            float n  = fmaxf(sqrtf(n2), MIN_NORM_C);
            float scale = 1.f;
            float n1 = n;
            if (n > maxnorm) { scale = maxnorm / n; n1 = maxnorm; }
            float xn = fmaxf(n1, MIN_NORM_C);
            float tval;
            if (k < 0.f) {
                float inner = fminf(sk * xn, 1.f - 1e-7f);
                float ar = atanhf(inner) / sk;          // artan_k
                tval = tanhf(sk * (0.5f * ar)) / sk;    // tan_k(0.5 * artan)
            } else {
                float ar = atanf(sk * xn) / sk;
                tval = tanf(sk * (0.5f * ar)) / sk;
            }
            float s2 = tval / xn;
            scale *= s2;
            float nrm2 = fmaxf(n1 * s2, MIN_NORM_C);
            if (nrm2 > maxnorm) scale *= maxnorm / nrm2;
            float4 o;
            o.x = x0 * scale; o.y = x1 * scale;
            o.z = x2 * scale; o.w = x3 * scale;
            int gtok = tbase + tt + row;
            *(float4*)(outp + (size_t)gtok * DH + tx * 4) = o;
        }
        __syncthreads();   // protect v1s/dinv before next tile
    }
}

extern "C" void kernel_launch(void* const* d_in, const int* in_sizes, int n_in,
                              void* d_out, int out_size, void* d_ws, size_t ws_size,
                              hipStream_t stream)
{
    const float* Q    = (const float*)d_in[0];
    const float* K    = (const float*)d_in[1];
    const float* V    = (const float*)d_in[2];
    const float* mask = (const float*)d_in[3];
    const float* c    = (const float*)d_in[4];
    const int csize   = in_sizes[4];
    const int BH      = in_sizes[0] / (NTOK * DH);   // 64
    const int H       = 16;
    float* out        = (float*)d_out;

    // workspace layout: pt[BH*NTOK] | v2sum[BH*64] | ctx[BH*64*64]
    float* pt    = (float*)d_ws;
    float* v2sum = pt + (size_t)BH * NTOK;
    float* ctx   = v2sum + (size_t)BH * DH;

    // zero the atomic accumulation region (ws is poisoned to 0xAA each launch)
    hipMemsetAsync(v2sum, 0,
                   ((size_t)BH * DH + (size_t)BH * DH * DH) * sizeof(float),
                   stream);

    dim3 grid(BH, NCHUNK);
    glin_phase1<<<grid, 256, 0, stream>>>(K, V, mask, c, csize, H, pt, v2sum, ctx);
    glin_phase2<<<grid, 256, 0, stream>>>(Q, c, csize, H, pt, v2sum, ctx, out);
}

// Round 3
// 349.920 us; speedup vs baseline: 3.5742x; 3.5742x over previous
//
#include <hip/hip_runtime.h>
#include <math.h>

#define EPS_C      1e-05f
#define PROJ_EPS_C 0.004f
#define MIN_NORM_C 1e-15f

#define NTOK   4096
#define DH     64
#define TILE   64
#define CHUNK  128
#define NCHUNK (NTOK / CHUNK)
#define PADROW 68   // 64 + 4 pad: float4-aligned rows, bank-stride 16 -> <=2-way

// component-wise FMA on named float4s: ACC += S * B  (no arrays -> no scratch)
#define FMA4(ACC, S, B)                      \
    ACC.x = fmaf((S), (B).x, ACC.x);         \
    ACC.y = fmaf((S), (B).y, ACC.y);         \
    ACC.z = fmaf((S), (B).z, ACC.z);         \
    ACC.w = fmaf((S), (B).w, ACC.w);

__device__ __forceinline__ float elup(float z) {
    // elu(z) + 1
    return z > 0.f ? z + 1.f : __expf(z);
}

// ---------------------------------------------------------------------------
// Phase 1: from K, V compute per-token pt, and accumulate v2_sum[64] and
// context[64][64] = sum_n v2[n][d] * x_scaled[n][e]  (atomicAdd into ws)
// ---------------------------------------------------------------------------
__global__ __launch_bounds__(256, 4) void glin_phase1(
    const float* __restrict__ Kk, const float* __restrict__ Vv,
    const float* __restrict__ mask, const float* __restrict__ cc,
    int csize, int H,
    float* __restrict__ pt_out, float* __restrict__ v2sum_out,
    float* __restrict__ ctx_out)
{
    __shared__ __align__(16) float v2s[TILE][PADROW];
    __shared__ __align__(16) float xss[TILE][PADROW];

    const int bh    = blockIdx.x;
    const int chunk = blockIdx.y;
    const int h     = bh % H;
    const float k   = cc[(csize == 1) ? 0 : h];

    const float* Kp = Kk + (size_t)bh * NTOK * DH;
    const float* Vp = Vv + (size_t)bh * NTOK * DH;
    float* ptp      = pt_out + (size_t)bh * NTOK;

    const int tid = threadIdx.x;
    const int ty  = tid >> 4;   // 0..15 -> d block
    const int tx  = tid & 15;   // 0..15 -> e block

    float4 acc0 = {0.f, 0.f, 0.f, 0.f};
    float4 acc1 = {0.f, 0.f, 0.f, 0.f};
    float4 acc2 = {0.f, 0.f, 0.f, 0.f};
    float4 acc3 = {0.f, 0.f, 0.f, 0.f};
    float4 v2acc = {0.f, 0.f, 0.f, 0.f};

    const int tbase = chunk * CHUNK;
    for (int tt = 0; tt < CHUNK; tt += TILE) {
        // ---- stage + transform one 64-token tile ----
#pragma unroll
        for (int p = 0; p < 4; ++p) {
            int f   = tid + p * 256;
            int row = f >> 4;       // local token 0..63
            int c4  = f & 15;       // float4 column 0..15
            int gtok = tbase + tt + row;
            float4 v4 = *(const float4*)(Vp + (size_t)gtok * DH + c4 * 4);
            float4 k4 = *(const float4*)(Kp + (size_t)gtok * DH + c4 * 4);
            // ||V_row||^2 via 16-lane reduction (lanes of same row are consecutive)
            float ss = v4.x * v4.x + v4.y * v4.y + v4.z * v4.z + v4.w * v4.w;
            ss += __shfl_xor(ss, 1);
            ss += __shfl_xor(ss, 2);
            ss += __shfl_xor(ss, 4);
            ss += __shfl_xor(ss, 8);
            float dpt   = fmaxf(1.f + k * ss, MIN_NORM_C);
            float pt    = 1.f / dpt;
            float gamma = 2.f * pt;
            float gm1   = gamma - 1.f;
            float sg    = (gm1 < 0.f) ? -1.f : 1.f;   // _sign(0) = +1
            float denomG = sg * fmaxf(fabsf(gm1), 1e-10f);
            float m     = mask[gtok];
            float xsc   = gamma / denomG * m;
            float a2    = denomG * m;
            if (c4 == 0) ptp[gtok] = pt;
            float4 xs4;
            xs4.x = v4.x * xsc; xs4.y = v4.y * xsc;
            xs4.z = v4.z * xsc; xs4.w = v4.w * xsc;
            float4 w4;
            w4.x = a2 * elup(k4.x * pt);
            w4.y = a2 * elup(k4.y * pt);
            w4.z = a2 * elup(k4.z * pt);
            w4.w = a2 * elup(k4.w * pt);
            *(float4*)&xss[row][c4 * 4] = xs4;
            *(float4*)&v2s[row][c4 * 4] = w4;
        }
        __syncthreads();
        // ---- outer-product accumulate: acc_i[j] += v2[t][ty*4+i] * xs[t][tx*4+j] ----
#pragma unroll 4
        for (int t = 0; t < TILE; ++t) {
            float4 a = *(const float4*)&v2s[t][ty * 4];
            float4 b = *(const float4*)&xss[t][tx * 4];
            v2acc.x += a.x; v2acc.y += a.y; v2acc.z += a.z; v2acc.w += a.w;
            FMA4(acc0, a.x, b);
            FMA4(acc1, a.y, b);
            FMA4(acc2, a.z, b);
            FMA4(acc3, a.w, b);
        }
        __syncthreads();
    }

    float* ctx = ctx_out + (size_t)bh * DH * DH;
#define CTX_ATOMIC(ACC, I)                                             \
    atomicAdd(&ctx[(ty * 4 + (I)) * DH + tx * 4 + 0], ACC.x);          \
    atomicAdd(&ctx[(ty * 4 + (I)) * DH + tx * 4 + 1], ACC.y);          \
    atomicAdd(&ctx[(ty * 4 + (I)) * DH + tx * 4 + 2], ACC.z);          \
    atomicAdd(&ctx[(ty * 4 + (I)) * DH + tx * 4 + 3], ACC.w);
    CTX_ATOMIC(acc0, 0)
    CTX_ATOMIC(acc1, 1)
    CTX_ATOMIC(acc2, 2)
    CTX_ATOMIC(acc3, 3)
#undef CTX_ATOMIC
    if (tx == 0) {
        float* vs = v2sum_out + (size_t)bh * DH + ty * 4;
        atomicAdd(vs + 0, v2acc.x);
        atomicAdd(vs + 1, v2acc.y);
        atomicAdd(vs + 2, v2acc.z);
        atomicAdd(vs + 3, v2acc.w);
    }
}

// ---------------------------------------------------------------------------
// Phase 2 epilogue: Dinv scale, project -> mobius(0.5) -> project, store.
// x holds 4 consecutive out-dims (tx*4..tx*4+3) of token `gtok`.
// ---------------------------------------------------------------------------
__device__ __forceinline__ void epilogue_store(
    float4 x, float dv, float k, float sk, float maxnorm,
    float* __restrict__ outp, int gtok, int tx)
{
    x.x *= dv; x.y *= dv; x.z *= dv; x.w *= dv;
    float n2 = x.x * x.x + x.y * x.y + x.z * x.z + x.w * x.w;
    n2 += __shfl_xor(n2, 1);
    n2 += __shfl_xor(n2, 2);
    n2 += __shfl_xor(n2, 4);
    n2 += __shfl_xor(n2, 8);
    float n  = fmaxf(sqrtf(n2), MIN_NORM_C);
    float scale = 1.f;
    float n1 = n;
    if (n > maxnorm) { scale = maxnorm / n; n1 = maxnorm; }
    float xn = fmaxf(n1, MIN_NORM_C);
    float tval;
    if (k < 0.f) {
        float inner = fminf(sk * xn, 1.f - 1e-7f);
        float ar = atanhf(inner) / sk;          // artan_k
        tval = tanhf(sk * (0.5f * ar)) / sk;    // tan_k(0.5 * artan)
    } else {
        float ar = atanf(sk * xn) / sk;
        tval = tanf(sk * (0.5f * ar)) / sk;
    }
    float s2 = tval / xn;
    scale *= s2;
    float nrm2 = fmaxf(n1 * s2, MIN_NORM_C);
    if (nrm2 > maxnorm) scale *= maxnorm / nrm2;
    float4 o;
    o.x = x.x * scale; o.y = x.y * scale;
    o.z = x.z * scale; o.w = x.w * scale;
    *(float4*)(outp + (size_t)gtok * DH + tx * 4) = o;
}

// ---------------------------------------------------------------------------
// Phase 2: from Q, pt, v2_sum, context compute
//   v1 = elup(Q*pt); D = v1.v2_sum; X = (v1 @ context)/D; project->mobius(0.5)->project
// ---------------------------------------------------------------------------
__global__ __launch_bounds__(256, 4) void glin_phase2(
    const float* __restrict__ Qq, const float* __restrict__ cc,
    int csize, int H,
    const float* __restrict__ pt_in, const float* __restrict__ v2sum_in,
    const float* __restrict__ ctx_in, float* __restrict__ out)
{
    __shared__ __align__(16) float ctxs[DH][PADROW];
    __shared__ __align__(16) float v1s[TILE][PADROW];  // natural [token][dim]
    __shared__ __align__(16) float v2sum[DH];
    __shared__ float dinv[TILE];
    __shared__ __align__(16) float ptl[CHUNK];

    const int bh    = blockIdx.x;
    const int chunk = blockIdx.y;
    const int h     = bh % H;
    const float k   = cc[(csize == 1) ? 0 : h];
    const float sk  = sqrtf(fabsf(k) + MIN_NORM_C);
    const float maxnorm = (k < 0.f) ? (1.f - PROJ_EPS_C) / sk : 1e15f;

    const int tid = threadIdx.x;
    const int ty  = tid >> 4;
    const int tx  = tid & 15;

    const float* Qp = Qq + (size_t)bh * NTOK * DH;
    float* outp     = out + (size_t)bh * NTOK * DH;

    // load context into LDS (padded)
#pragma unroll
    for (int p = 0; p < 4; ++p) {
        int f = tid + p * 256;
        int d = f >> 4, c4 = f & 15;
        float4 v = *(const float4*)(ctx_in + (size_t)bh * DH * DH + d * DH + c4 * 4);
        *(float4*)&ctxs[d][c4 * 4] = v;
    }
    if (tid < 16) {
        float4 v = *(const float4*)(v2sum_in + (size_t)bh * DH + tid * 4);
        *(float4*)&v2sum[tid * 4] = v;
    }
    if (tid < CHUNK / 4) {
        float4 v = *(const float4*)(pt_in + (size_t)bh * NTOK + chunk * CHUNK + tid * 4);
        *(float4*)&ptl[tid * 4] = v;
    }
    __syncthreads();

    const int tbase = chunk * CHUNK;
    for (int tt = 0; tt < CHUNK; tt += TILE) {
        // ---- build v1 tile (natural layout) + Dinv ----
#pragma unroll
        for (int p = 0; p < 4; ++p) {
            int f   = tid + p * 256;
            int row = f >> 4;        // local token 0..63
            int c4  = f & 15;
            int gtok = tbase + tt + row;
            float4 q4 = *(const float4*)(Qp + (size_t)gtok * DH + c4 * 4);
            float ptv = ptl[tt + row];
            float4 v1;
            v1.x = elup(q4.x * ptv);
            v1.y = elup(q4.y * ptv);
            v1.z = elup(q4.z * ptv);
            v1.w = elup(q4.w * ptv);
            float4 vs = *(const float4*)&v2sum[c4 * 4];
            float dp = v1.x * vs.x + v1.y * vs.y + v1.z * vs.z + v1.w * vs.w;
            dp += __shfl_xor(dp, 1);
            dp += __shfl_xor(dp, 2);
            dp += __shfl_xor(dp, 4);
            dp += __shfl_xor(dp, 8);
            if (c4 == 0) {
                float Dv = (dp == 0.f) ? EPS_C : dp;
                dinv[row] = 1.f / Dv;
            }
            *(float4*)&v1s[row][c4 * 4] = v1;
        }
        __syncthreads();
        // ---- X_tile = v1 @ context : 4 tokens (acc0..3) x 4 out-dims ----
        float4 acc0 = {0.f, 0.f, 0.f, 0.f};
        float4 acc1 = {0.f, 0.f, 0.f, 0.f};
        float4 acc2 = {0.f, 0.f, 0.f, 0.f};
        float4 acc3 = {0.f, 0.f, 0.f, 0.f};
#pragma unroll 4
        for (int db = 0; db < DH / 4; ++db) {
            float4 b0 = *(const float4*)&ctxs[db * 4 + 0][tx * 4];
            float4 b1 = *(const float4*)&ctxs[db * 4 + 1][tx * 4];
            float4 b2 = *(const float4*)&ctxs[db * 4 + 2][tx * 4];
            float4 b3 = *(const float4*)&ctxs[db * 4 + 3][tx * 4];
            float4 a0 = *(const float4*)&v1s[ty * 4 + 0][db * 4];
            FMA4(acc0, a0.x, b0); FMA4(acc0, a0.y, b1);
            FMA4(acc0, a0.z, b2); FMA4(acc0, a0.w, b3);
            float4 a1 = *(const float4*)&v1s[ty * 4 + 1][db * 4];
            FMA4(acc1, a1.x, b0); FMA4(acc1, a1.y, b1);
            FMA4(acc1, a1.z, b2); FMA4(acc1, a1.w, b3);
            float4 a2 = *(const float4*)&v1s[ty * 4 + 2][db * 4];
            FMA4(acc2, a2.x, b0); FMA4(acc2, a2.y, b1);
            FMA4(acc2, a2.z, b2); FMA4(acc2, a2.w, b3);
            float4 a3 = *(const float4*)&v1s[ty * 4 + 3][db * 4];
            FMA4(acc3, a3.x, b0); FMA4(acc3, a3.y, b1);
            FMA4(acc3, a3.z, b2); FMA4(acc3, a3.w, b3);
        }
        // ---- epilogue per token ----
        epilogue_store(acc0, dinv[ty * 4 + 0], k, sk, maxnorm, outp, tbase + tt + ty * 4 + 0, tx);
        epilogue_store(acc1, dinv[ty * 4 + 1], k, sk, maxnorm, outp, tbase + tt + ty * 4 + 1, tx);
        epilogue_store(acc2, dinv[ty * 4 + 2], k, sk, maxnorm, outp, tbase + tt + ty * 4 + 2, tx);
        epilogue_store(acc3, dinv[ty * 4 + 3], k, sk, maxnorm, outp, tbase + tt + ty * 4 + 3, tx);
        __syncthreads();   // protect v1s/dinv before next tile
    }
}

extern "C" void kernel_launch(void* const* d_in, const int* in_sizes, int n_in,
                              void* d_out, int out_size, void* d_ws, size_t ws_size,
                              hipStream_t stream)
{
    const float* Q    = (const float*)d_in[0];
    const float* K    = (const float*)d_in[1];
    const float* V    = (const float*)d_in[2];
    const float* mask = (const float*)d_in[3];
    const float* c    = (const float*)d_in[4];
    const int csize   = in_sizes[4];
    const int BH      = in_sizes[0] / (NTOK * DH);   // 64
    const int H       = 16;
    float* out        = (float*)d_out;

    // workspace layout: pt[BH*NTOK] | v2sum[BH*64] | ctx[BH*64*64]
    float* pt    = (float*)d_ws;
    float* v2sum = pt + (size_t)BH * NTOK;
    float* ctx   = v2sum + (size_t)BH * DH;

    // zero the atomic accumulation region (ws is poisoned to 0xAA each launch)
    hipMemsetAsync(v2sum, 0,
                   ((size_t)BH * DH + (size_t)BH * DH * DH) * sizeof(float),
                   stream);

    dim3 grid(BH, NCHUNK);
    glin_phase1<<<grid, 256, 0, stream>>>(K, V, mask, c, csize, H, pt, v2sum, ctx);
    glin_phase2<<<grid, 256, 0, stream>>>(Q, c, csize, H, pt, v2sum, ctx, out);
}

// Round 4
// 291.610 us; speedup vs baseline: 4.2888x; 1.2000x over previous
//
#include <hip/hip_runtime.h>
#include <math.h>

#define EPS_C      1e-05f
#define PROJ_EPS_C 0.004f
#define MIN_NORM_C 1e-15f

#define NTOK   4096
#define DH     64
#define TILE   64
#define CHUNK2 128                 // phase2 tokens per block
#define NCHUNK2 (NTOK / CHUNK2)
#define PADROW 68

// component-wise FMA on named float4s: ACC += S * B  (no arrays -> no scratch)
#define FMA4(ACC, S, B)                      \
    ACC.x = fmaf((S), (B).x, ACC.x);         \
    ACC.y = fmaf((S), (B).y, ACC.y);         \
    ACC.z = fmaf((S), (B).z, ACC.z);         \
    ACC.w = fmaf((S), (B).w, ACC.w);

__device__ __forceinline__ float elup(float z) {
    // elu(z) + 1
    return z > 0.f ? z + 1.f : __expf(z);
}

// ---------------------------------------------------------------------------
// Phase 1: from K, V compute per-token pt, and per-chunk PARTIAL v2_sum[64]
// and context[64][64] tiles (plain coalesced stores -- no atomics).
// ---------------------------------------------------------------------------
__global__ __launch_bounds__(256, 4) void glin_phase1(
    const float* __restrict__ Kk, const float* __restrict__ Vv,
    const float* __restrict__ mask, const float* __restrict__ cc,
    int csize, int H, int chunk_toks, int BH,
    float* __restrict__ pt_out,
    float* __restrict__ part_v2, float* __restrict__ part_ctx)
{
    __shared__ __align__(16) float v2s[TILE][PADROW];
    __shared__ __align__(16) float xss[TILE][PADROW];

    const int bh    = blockIdx.x;
    const int chunk = blockIdx.y;
    const int h     = bh % H;
    const float k   = cc[(csize == 1) ? 0 : h];

    const float* Kp = Kk + (size_t)bh * NTOK * DH;
    const float* Vp = Vv + (size_t)bh * NTOK * DH;
    float* ptp      = pt_out + (size_t)bh * NTOK;

    const int tid = threadIdx.x;
    const int ty  = tid >> 4;   // 0..15 -> d block
    const int tx  = tid & 15;   // 0..15 -> e block

    float4 acc0 = {0.f, 0.f, 0.f, 0.f};
    float4 acc1 = {0.f, 0.f, 0.f, 0.f};
    float4 acc2 = {0.f, 0.f, 0.f, 0.f};
    float4 acc3 = {0.f, 0.f, 0.f, 0.f};
    float4 v2acc = {0.f, 0.f, 0.f, 0.f};

    const int tbase = chunk * chunk_toks;
    for (int tt = 0; tt < chunk_toks; tt += TILE) {
        // ---- stage + transform one 64-token tile ----
#pragma unroll
        for (int p = 0; p < 4; ++p) {
            int f   = tid + p * 256;
            int row = f >> 4;       // local token 0..63
            int c4  = f & 15;       // float4 column 0..15
            int gtok = tbase + tt + row;
            float4 v4 = *(const float4*)(Vp + (size_t)gtok * DH + c4 * 4);
            float4 k4 = *(const float4*)(Kp + (size_t)gtok * DH + c4 * 4);
            // ||V_row||^2 via 16-lane reduction (lanes of same row are consecutive)
            float ss = v4.x * v4.x + v4.y * v4.y + v4.z * v4.z + v4.w * v4.w;
            ss += __shfl_xor(ss, 1);
            ss += __shfl_xor(ss, 2);
            ss += __shfl_xor(ss, 4);
            ss += __shfl_xor(ss, 8);
            float dpt   = fmaxf(1.f + k * ss, MIN_NORM_C);
            float pt    = 1.f / dpt;
            float gamma = 2.f * pt;
            float gm1   = gamma - 1.f;
            float sg    = (gm1 < 0.f) ? -1.f : 1.f;   // _sign(0) = +1
            float denomG = sg * fmaxf(fabsf(gm1), 1e-10f);
            float m     = mask[gtok];
            float xsc   = gamma / denomG * m;
            float a2    = denomG * m;
            if (c4 == 0) ptp[gtok] = pt;
            float4 xs4;
            xs4.x = v4.x * xsc; xs4.y = v4.y * xsc;
            xs4.z = v4.z * xsc; xs4.w = v4.w * xsc;
            float4 w4;
            w4.x = a2 * elup(k4.x * pt);
            w4.y = a2 * elup(k4.y * pt);
            w4.z = a2 * elup(k4.z * pt);
            w4.w = a2 * elup(k4.w * pt);
            *(float4*)&xss[row][c4 * 4] = xs4;
            *(float4*)&v2s[row][c4 * 4] = w4;
        }
        __syncthreads();
        // ---- outer-product accumulate: acc_i[j] += v2[t][ty*4+i] * xs[t][tx*4+j] ----
#pragma unroll 8
        for (int t = 0; t < TILE; ++t) {
            float4 a = *(const float4*)&v2s[t][ty * 4];
            float4 b = *(const float4*)&xss[t][tx * 4];
            v2acc.x += a.x; v2acc.y += a.y; v2acc.z += a.z; v2acc.w += a.w;
            FMA4(acc0, a.x, b);
            FMA4(acc1, a.y, b);
            FMA4(acc2, a.z, b);
            FMA4(acc3, a.w, b);
        }
        __syncthreads();
    }

    // plain coalesced partial stores (replaces 16 atomics/thread)
    float* pc = part_ctx + ((size_t)chunk * BH + bh) * (DH * DH);
    *(float4*)&pc[(ty * 4 + 0) * DH + tx * 4] = acc0;
    *(float4*)&pc[(ty * 4 + 1) * DH + tx * 4] = acc1;
    *(float4*)&pc[(ty * 4 + 2) * DH + tx * 4] = acc2;
    *(float4*)&pc[(ty * 4 + 3) * DH + tx * 4] = acc3;
    if (tx == 0) {
        float* pv = part_v2 + ((size_t)chunk * BH + bh) * DH;
        *(float4*)&pv[ty * 4] = v2acc;
    }
}

// ---------------------------------------------------------------------------
// Reduce partials: ctx[bh][e] = sum_c part_ctx[c][bh][e]; same for v2sum.
// grid (BH, 4), 256 threads; each thread sums 4 ctx elements.
// ---------------------------------------------------------------------------
__global__ __launch_bounds__(256) void glin_reduce(
    const float* __restrict__ part_ctx, const float* __restrict__ part_v2,
    int P, int BH,
    float* __restrict__ ctx_out, float* __restrict__ v2sum_out)
{
    const int bh  = blockIdx.x;
    const int q   = blockIdx.y;
    const int tid = threadIdx.x;
    const int base = q * 1024 + tid;   // elems base + {0,256,512,768}

    float s0 = 0.f, s1 = 0.f, s2 = 0.f, s3 = 0.f;
    for (int c = 0; c < P; ++c) {
        const float* p = part_ctx + ((size_t)c * BH + bh) * (DH * DH);
        s0 += p[base];
        s1 += p[base + 256];
        s2 += p[base + 512];
        s3 += p[base + 768];
    }
    float* co = ctx_out + (size_t)bh * DH * DH;
    co[base] = s0; co[base + 256] = s1; co[base + 512] = s2; co[base + 768] = s3;

    if (q == 0 && tid < DH) {
        float s = 0.f;
        for (int c = 0; c < P; ++c)
            s += part_v2[((size_t)c * BH + bh) * DH + tid];
        v2sum_out[(size_t)bh * DH + tid] = s;
    }
}

// ---------------------------------------------------------------------------
// Phase 2 epilogue: Dinv scale, project -> mobius(0.5) -> project, store.
// Closed form: tan_k(0.5*artan_k(n)) / n = 1 / (1 + sqrt(1 - sign(k)*(sk*n)^2))
// ---------------------------------------------------------------------------
__device__ __forceinline__ void epilogue_store(
    float4 x, float dv, float k, float sk, float maxnorm,
    float* __restrict__ outp, int gtok, int tx)
{
    x.x *= dv; x.y *= dv; x.z *= dv; x.w *= dv;
    float n2 = x.x * x.x + x.y * x.y + x.z * x.z + x.w * x.w;
    n2 += __shfl_xor(n2, 1);
    n2 += __shfl_xor(n2, 2);
    n2 += __shfl_xor(n2, 4);
    n2 += __shfl_xor(n2, 8);
    float n  = fmaxf(sqrtf(n2), MIN_NORM_C);
    float scale = 1.f;
    float n1 = n;
    if (n > maxnorm) { scale = maxnorm / n; n1 = maxnorm; }
    float xn = fmaxf(n1, MIN_NORM_C);
    float s2;
    if (k < 0.f) {
        float t = fminf(sk * xn, 1.f - 1e-7f);
        s2 = 1.f / (1.f + sqrtf(fmaxf(1.f - t * t, 0.f)));
    } else {
        float t = sk * xn;
        s2 = 1.f / (1.f + sqrtf(1.f + t * t));
    }
    scale *= s2;
    float nrm2 = fmaxf(n1 * s2, MIN_NORM_C);
    if (nrm2 > maxnorm) scale *= maxnorm / nrm2;
    float4 o;
    o.x = x.x * scale; o.y = x.y * scale;
    o.z = x.z * scale; o.w = x.w * scale;
    *(float4*)(outp + (size_t)gtok * DH + tx * 4) = o;
}

// ---------------------------------------------------------------------------
// Phase 2: v1 = elup(Q*pt); D = v1.v2_sum; X = (v1 @ ctx)/D; epilogue.
// ---------------------------------------------------------------------------
__global__ __launch_bounds__(256, 4) void glin_phase2(
    const float* __restrict__ Qq, const float* __restrict__ cc,
    int csize, int H,
    const float* __restrict__ pt_in, const float* __restrict__ v2sum_in,
    const float* __restrict__ ctx_in, float* __restrict__ out)
{
    __shared__ __align__(16) float ctxs[DH][PADROW];
    __shared__ __align__(16) float v1s[TILE][PADROW];  // natural [token][dim]
    __shared__ __align__(16) float v2sum[DH];
    __shared__ float dinv[TILE];
    __shared__ __align__(16) float ptl[CHUNK2];

    const int bh    = blockIdx.x;
    const int chunk = blockIdx.y;
    const int h     = bh % H;
    const float k   = cc[(csize == 1) ? 0 : h];
    const float sk  = sqrtf(fabsf(k) + MIN_NORM_C);
    const float maxnorm = (k < 0.f) ? (1.f - PROJ_EPS_C) / sk : 1e15f;

    const int tid = threadIdx.x;
    const int ty  = tid >> 4;
    const int tx  = tid & 15;

    const float* Qp = Qq + (size_t)bh * NTOK * DH;
    float* outp     = out + (size_t)bh * NTOK * DH;

    // load context into LDS (padded)
#pragma unroll
    for (int p = 0; p < 4; ++p) {
        int f = tid + p * 256;
        int d = f >> 4, c4 = f & 15;
        float4 v = *(const float4*)(ctx_in + (size_t)bh * DH * DH + d * DH + c4 * 4);
        *(float4*)&ctxs[d][c4 * 4] = v;
    }
    if (tid < 16) {
        float4 v = *(const float4*)(v2sum_in + (size_t)bh * DH + tid * 4);
        *(float4*)&v2sum[tid * 4] = v;
    }
    if (tid < CHUNK2 / 4) {
        float4 v = *(const float4*)(pt_in + (size_t)bh * NTOK + chunk * CHUNK2 + tid * 4);
        *(float4*)&ptl[tid * 4] = v;
    }
    __syncthreads();

    const int tbase = chunk * CHUNK2;
    for (int tt = 0; tt < CHUNK2; tt += TILE) {
        // ---- build v1 tile (natural layout) + Dinv ----
#pragma unroll
        for (int p = 0; p < 4; ++p) {
            int f   = tid + p * 256;
            int row = f >> 4;        // local token 0..63
            int c4  = f & 15;
            int gtok = tbase + tt + row;
            float4 q4 = *(const float4*)(Qp + (size_t)gtok * DH + c4 * 4);
            float ptv = ptl[tt + row];
            float4 v1;
            v1.x = elup(q4.x * ptv);
            v1.y = elup(q4.y * ptv);
            v1.z = elup(q4.z * ptv);
            v1.w = elup(q4.w * ptv);
            float4 vs = *(const float4*)&v2sum[c4 * 4];
            float dp = v1.x * vs.x + v1.y * vs.y + v1.z * vs.z + v1.w * vs.w;
            dp += __shfl_xor(dp, 1);
            dp += __shfl_xor(dp, 2);
            dp += __shfl_xor(dp, 4);
            dp += __shfl_xor(dp, 8);
            if (c4 == 0) {
                float Dv = (dp == 0.f) ? EPS_C : dp;
                dinv[row] = 1.f / Dv;
            }
            *(float4*)&v1s[row][c4 * 4] = v1;
        }
        __syncthreads();
        // ---- X_tile = v1 @ context : 4 tokens (acc0..3) x 4 out-dims ----
        float4 acc0 = {0.f, 0.f, 0.f, 0.f};
        float4 acc1 = {0.f, 0.f, 0.f, 0.f};
        float4 acc2 = {0.f, 0.f, 0.f, 0.f};
        float4 acc3 = {0.f, 0.f, 0.f, 0.f};
#pragma unroll 8
        for (int db = 0; db < DH / 4; ++db) {
            float4 b0 = *(const float4*)&ctxs[db * 4 + 0][tx * 4];
            float4 b1 = *(const float4*)&ctxs[db * 4 + 1][tx * 4];
            float4 b2 = *(const float4*)&ctxs[db * 4 + 2][tx * 4];
            float4 b3 = *(const float4*)&ctxs[db * 4 + 3][tx * 4];
            float4 a0 = *(const float4*)&v1s[ty * 4 + 0][db * 4];
            FMA4(acc0, a0.x, b0); FMA4(acc0, a0.y, b1);
            FMA4(acc0, a0.z, b2); FMA4(acc0, a0.w, b3);
            float4 a1 = *(const float4*)&v1s[ty * 4 + 1][db * 4];
            FMA4(acc1, a1.x, b0); FMA4(acc1, a1.y, b1);
            FMA4(acc1, a1.z, b2); FMA4(acc1, a1.w, b3);
            float4 a2 = *(const float4*)&v1s[ty * 4 + 2][db * 4];
            FMA4(acc2, a2.x, b0); FMA4(acc2, a2.y, b1);
            FMA4(acc2, a2.z, b2); FMA4(acc2, a2.w, b3);
            float4 a3 = *(const float4*)&v1s[ty * 4 + 3][db * 4];
            FMA4(acc3, a3.x, b0); FMA4(acc3, a3.y, b1);
            FMA4(acc3, a3.z, b2); FMA4(acc3, a3.w, b3);
        }
        // ---- epilogue per token ----
        epilogue_store(acc0, dinv[ty * 4 + 0], k, sk, maxnorm, outp, tbase + tt + ty * 4 + 0, tx);
        epilogue_store(acc1, dinv[ty * 4 + 1], k, sk, maxnorm, outp, tbase + tt + ty * 4 + 1, tx);
        epilogue_store(acc2, dinv[ty * 4 + 2], k, sk, maxnorm, outp, tbase + tt + ty * 4 + 2, tx);
        epilogue_store(acc3, dinv[ty * 4 + 3], k, sk, maxnorm, outp, tbase + tt + ty * 4 + 3, tx);
        __syncthreads();   // protect v1s/dinv before next tile
    }
}

extern "C" void kernel_launch(void* const* d_in, const int* in_sizes, int n_in,
                              void* d_out, int out_size, void* d_ws, size_t ws_size,
                              hipStream_t stream)
{
    const float* Q    = (const float*)d_in[0];
    const float* K    = (const float*)d_in[1];
    const float* V    = (const float*)d_in[2];
    const float* mask = (const float*)d_in[3];
    const float* c    = (const float*)d_in[4];
    const int csize   = in_sizes[4];
    const int BH      = in_sizes[0] / (NTOK * DH);   // 64
    const int H       = 16;
    float* out        = (float*)d_out;

    // pick largest partial-chunk count P that fits the workspace
    int P = 16;
    while (P > 1) {
        size_t need = ((size_t)BH * NTOK                 // pt
                     + (size_t)BH * DH                   // v2sum
                     + (size_t)BH * DH * DH              // ctx
                     + (size_t)P * BH * DH               // part_v2
                     + (size_t)P * BH * DH * DH)         // part_ctx
                     * sizeof(float);
        if (need <= ws_size) break;
        P >>= 1;
    }
    const int chunk_toks = NTOK / P;

    // workspace layout
    float* pt       = (float*)d_ws;
    float* v2sum    = pt + (size_t)BH * NTOK;
    float* ctx      = v2sum + (size_t)BH * DH;
    float* part_v2  = ctx + (size_t)BH * DH * DH;
    float* part_ctx = part_v2 + (size_t)P * BH * DH;

    dim3 g1(BH, P);
    glin_phase1<<<g1, 256, 0, stream>>>(K, V, mask, c, csize, H, chunk_toks, BH,
                                        pt, part_v2, part_ctx);
    dim3 gr(BH, 4);
    glin_reduce<<<gr, 256, 0, stream>>>(part_ctx, part_v2, P, BH, ctx, v2sum);
    dim3 g2(BH, NCHUNK2);
    glin_phase2<<<g2, 256, 0, stream>>>(Q, c, csize, H, pt, v2sum, ctx, out);
}